// Round 7
// baseline (3512.944 us; speedup 1.0000x reference)
//
#include <hip/hip_runtime.h>

#define BATCH   8
#define NPTS    16384
#define NCH     128
#define NPOINT  1024
#define NSAMPLE 64
#define CIN     131   // 3 + NCH

#define FPS_PAIRS   4                       // pair g -> batches g and g+4
#define FPS_SUBS    4                       // blocks per batch
#define FPS_THREADS 512
#define FPS_PPT     ((NPTS / FPS_SUBS) / FPS_THREADS)   // 8 points per thread

typedef unsigned long long u64;

__device__ __forceinline__ u64 u64max(u64 a, u64 b) { return a > b ? a : b; }

__device__ __forceinline__ u64 shfl_xor_u64(u64 v, int off) {
  const unsigned lo = __shfl_xor((unsigned)v, off, 64);
  const unsigned hi = __shfl_xor((unsigned)(v >> 32), off, 64);
  return ((u64)hi << 32) | lo;
}
__device__ __forceinline__ u64 shfl_u64(u64 v, int src) {
  const unsigned lo = __shfl((unsigned)v, src, 64);
  const unsigned hi = __shfl((unsigned)(v >> 32), src, 64);
  return ((u64)hi << 32) | lo;
}

// Poll 4 subs x 5 tagged words {val,idx,x,y,z}; winner = max val, tie -> lowest
// sub (subs own ascending index ranges => numpy first-occurrence preserved).
__device__ __forceinline__ void poll_select(
    const u64* __restrict__ slots, int k, int lane,
    float& px, float& py, float& pz, int& widx)
{
  const int sub = lane >> 3, word = lane & 7;
  const bool active = (lane < 32) && (word < 5);
  u64 v = 0;
  if (active) {
    do {
      v = __hip_atomic_load(slots + sub * 8 + word, __ATOMIC_RELAXED,
                            __HIP_MEMORY_SCOPE_AGENT);
    } while ((int)(v >> 32) != k);
  }
  // butterfly max over lanes {0,8,16,24}; key = val<<2 | (3-sub)
  u64 key = ((u64)(unsigned)v << 2) | (u64)(3 - (sub & 3));
  key = u64max(key, shfl_xor_u64(key, 8));
  key = u64max(key, shfl_xor_u64(key, 16));
  const int wsub = 3 - (int)(shfl_u64(key, 0) & 3);
  widx = (int)(unsigned)shfl_u64(v, wsub * 8 + 1);
  px = __uint_as_float((unsigned)shfl_u64(v, wsub * 8 + 2));
  py = __uint_as_float((unsigned)shfl_u64(v, wsub * 8 + 3));
  pz = __uint_as_float((unsigned)shfl_u64(v, wsub * 8 + 4));
}

// Exact numpy order: d = ((dx*dx + dy*dy) + dz*dz), no fma; fminf; argmax
// first-occurrence. pk = valbits<<18 | (idx ^ 0x3FFFF): u64-max == (val max,
// idx min). Winning thread also keeps the point's raw coords in registers.
#define FPS_STEP(xs, ys, zs, mind, px, py, pz, pkm, bx, by, bz)                \
  {                                                                            \
    float bestv = -1.0f; int besti = 0;                                        \
    _Pragma("unroll")                                                          \
    for (int i = 0; i < FPS_PPT; ++i) {                                        \
      const float dx = xs[i] - px, dy = ys[i] - py, dz = zs[i] - pz;           \
      const float d = __fadd_rn(__fadd_rn(__fmul_rn(dx, dx), __fmul_rn(dy, dy)),\
                                __fmul_rn(dz, dz));                            \
      const float m = fminf(mind[i], d);                                       \
      mind[i] = m;                                                             \
      if (m > bestv) { bestv = m; besti = base + t + i * FPS_THREADS;          \
                       bx = xs[i]; by = ys[i]; bz = zs[i]; }                   \
    }                                                                          \
    pkm = ((u64)__float_as_uint(bestv) << 18) | (u64)(besti ^ 0x3FFFF);        \
  }

#define FPS_PUBLISH(slots, k, bw, bx, by, bz)                                  \
  {                                                                            \
    const u64 tg = (u64)(k) << 32;                                             \
    u64* __restrict__ sl = (slots) + ((k) & 1) * (FPS_SUBS * 8) + s * 8;       \
    __hip_atomic_store(&sl[1], tg | (unsigned)(((bw) ^ 0x3FFFF) & 0x3FFFF),    \
                       __ATOMIC_RELAXED, __HIP_MEMORY_SCOPE_AGENT);            \
    __hip_atomic_store(&sl[2], tg | __float_as_uint(bx),                       \
                       __ATOMIC_RELAXED, __HIP_MEMORY_SCOPE_AGENT);            \
    __hip_atomic_store(&sl[3], tg | __float_as_uint(by),                       \
                       __ATOMIC_RELAXED, __HIP_MEMORY_SCOPE_AGENT);            \
    __hip_atomic_store(&sl[4], tg | __float_as_uint(bz),                       \
                       __ATOMIC_RELAXED, __HIP_MEMORY_SCOPE_AGENT);            \
    __hip_atomic_store(&sl[0], tg | (unsigned)((bw) >> 18),                    \
                       __ATOMIC_RELAXED, __HIP_MEMORY_SCOPE_AGENT);            \
    asm volatile("" ::: "memory");                                             \
  }

// ---------------------------------------------------------------------------
// Pipelined multi-block FPS: 16 blocks; block (g,s) owns sub s of batches g
// and g+4, interleaved half an iteration apart so each publish has ~1000 cy
// of the other stream's compute before its matching poll (latency hidden).
// ---------------------------------------------------------------------------
__global__ __launch_bounds__(FPS_THREADS) void fps_pipe_kernel(
    const float* __restrict__ xyz, float* __restrict__ out_newxyz,
    float* __restrict__ out_inds_f, u64* __restrict__ sync)
{
  const int bid = blockIdx.x;
  const int g   = bid & 3;          // pair
  const int s   = bid >> 2;         // sub 0..3
  const int bA  = g, bB = g + 4;
  const int t = threadIdx.x, lane = t & 63, wid = t >> 6;
  const int base = s * (NPTS / FPS_SUBS);

  const float* __restrict__ pA = xyz + (size_t)bA * NPTS * 3;
  const float* __restrict__ pB = xyz + (size_t)bB * NPTS * 3;

  float axs[FPS_PPT], ays[FPS_PPT], azs[FPS_PPT], amind[FPS_PPT];
  float bxs[FPS_PPT], bys[FPS_PPT], bzs[FPS_PPT], bmind[FPS_PPT];
#pragma unroll
  for (int i = 0; i < FPS_PPT; ++i) {
    const int n = base + t + i * FPS_THREADS;   // coalesced per wave
    axs[i] = pA[n * 3 + 0]; ays[i] = pA[n * 3 + 1]; azs[i] = pA[n * 3 + 2];
    bxs[i] = pB[n * 3 + 0]; bys[i] = pB[n * 3 + 1]; bzs[i] = pB[n * 3 + 2];
    amind[i] = 1e10f; bmind[i] = 1e10f;
  }

  __shared__ u64 s_wA[FPS_THREADS / 64], s_wB[FPS_THREADS / 64];

  u64* __restrict__ slotsA = sync + (size_t)bA * (2 * FPS_SUBS * 8);
  u64* __restrict__ slotsB = sync + (size_t)bB * (2 * FPS_SUBS * 8);

  float pxA = pA[0], pyA = pA[1], pzA = pA[2];
  float pxB = pB[0], pyB = pB[1], pzB = pB[2];
  if (s == 0 && t == 0) {
    out_inds_f[bA * NPOINT] = 0.0f;
    out_inds_f[bB * NPOINT] = 0.0f;
    size_t oA = (size_t)bA * NPOINT * 3, oB = (size_t)bB * NPOINT * 3;
    out_newxyz[oA + 0] = pxA; out_newxyz[oA + 1] = pyA; out_newxyz[oA + 2] = pzA;
    out_newxyz[oB + 0] = pxB; out_newxyz[oB + 1] = pyB; out_newxyz[oB + 2] = pzB;
  }

  for (int k = 1; k < NPOINT; ++k) {
    // ---- stream A: candidate for iteration k, publish
    u64 pkA; float cxA = 0.f, cyA = 0.f, czA = 0.f;
    FPS_STEP(axs, ays, azs, amind, pxA, pyA, pzA, pkA, cxA, cyA, czA);
    {
      u64 r = pkA;
#pragma unroll
      for (int off = 32; off >= 1; off >>= 1) r = u64max(r, shfl_xor_u64(r, off));
      if (lane == 0) s_wA[wid] = r;
    }
    __syncthreads();
    {
      u64 bw = s_wA[0];
#pragma unroll
      for (int i = 1; i < FPS_THREADS / 64; ++i) bw = u64max(bw, s_wA[i]);
      if (pkA == bw) FPS_PUBLISH(slotsA, k, bw, cxA, cyA, czA);
    }

    // ---- stream B: collect winner of k-1 (published last iteration)
    if (k > 1) {
      int widx;
      poll_select(slotsB + ((k - 1) & 1) * (FPS_SUBS * 8), k - 1, lane,
                  pxB, pyB, pzB, widx);
      if (s == 0 && t == 0) {
        out_inds_f[bB * NPOINT + (k - 1)] = (float)widx;
        const size_t o = ((size_t)bB * NPOINT + (k - 1)) * 3;
        out_newxyz[o + 0] = pxB; out_newxyz[o + 1] = pyB; out_newxyz[o + 2] = pzB;
      }
    }

    // ---- stream B: candidate for iteration k, publish
    u64 pkB; float cxB = 0.f, cyB = 0.f, czB = 0.f;
    FPS_STEP(bxs, bys, bzs, bmind, pxB, pyB, pzB, pkB, cxB, cyB, czB);
    {
      u64 r = pkB;
#pragma unroll
      for (int off = 32; off >= 1; off >>= 1) r = u64max(r, shfl_xor_u64(r, off));
      if (lane == 0) s_wB[wid] = r;
    }
    __syncthreads();
    {
      u64 bw = s_wB[0];
#pragma unroll
      for (int i = 1; i < FPS_THREADS / 64; ++i) bw = u64max(bw, s_wB[i]);
      if (pkB == bw) FPS_PUBLISH(slotsB, k, bw, cxB, cyB, czB);
    }

    // ---- stream A: collect winner of k (published ~1 stream-step ago)
    {
      int widx;
      poll_select(slotsA + (k & 1) * (FPS_SUBS * 8), k, lane,
                  pxA, pyA, pzA, widx);
      if (s == 0 && t == 0) {
        out_inds_f[bA * NPOINT + k] = (float)widx;
        const size_t o = ((size_t)bA * NPOINT + k) * 3;
        out_newxyz[o + 0] = pxA; out_newxyz[o + 1] = pyA; out_newxyz[o + 2] = pzA;
      }
    }
  }

  // epilogue: stream B's final winner
  {
    int widx;
    poll_select(slotsB + ((NPOINT - 1) & 1) * (FPS_SUBS * 8), NPOINT - 1, lane,
                pxB, pyB, pzB, widx);
    if (s == 0 && t == 0) {
      out_inds_f[bB * NPOINT + (NPOINT - 1)] = (float)widx;
      const size_t o = ((size_t)bB * NPOINT + (NPOINT - 1)) * 3;
      out_newxyz[o + 0] = pxB; out_newxyz[o + 1] = pyB; out_newxyz[o + 2] = pzB;
    }
  }
}

// ---------------------------------------------------------------------------
// Transpose weights into [ic][oc] layout so MLP threads can float4-load
// 4 (or 8) output channels per K-step.
// ---------------------------------------------------------------------------
__global__ void wtrans_kernel(const float* __restrict__ W0,
                              const float* __restrict__ W1,
                              const float* __restrict__ W2,
                              float* __restrict__ w0t,
                              float* __restrict__ w1t,
                              float* __restrict__ w2t)
{
  const int t = blockIdx.x * blockDim.x + threadIdx.x;
  if (t < 64 * CIN) { const int oc = t / CIN, ic = t % CIN; w0t[ic * 64  + oc] = W0[t]; }
  if (t < 64 * 64)  { const int oc = t >> 6,  ic = t & 63;  w1t[ic * 64  + oc] = W1[t]; }
  if (t < 128 * 64) { const int oc = t / 64,  ic = t % 64;  w2t[ic * 128 + oc] = W2[t]; }
}

// ---------------------------------------------------------------------------
// Ball query: one wave per center. First NSAMPLE indices (ascending) with
// d2 < r^2; pad remaining slots with the first in-ball index.
// ---------------------------------------------------------------------------
__global__ __launch_bounds__(256) void ballquery_kernel(
    const float* __restrict__ xyz, const float* __restrict__ newxyz,
    int* __restrict__ ballidx)
{
  const int gw   = (blockIdx.x * 256 + threadIdx.x) >> 6;  // global wave = center
  const int lane = threadIdx.x & 63;
  const int b    = gw >> 10;
  const float R2 = (float)(0.3 * 0.3);   // fl32(0.09), matches numpy weak cast

  const float cx = newxyz[gw * 3 + 0];
  const float cy = newxyz[gw * 3 + 1];
  const float cz = newxyz[gw * 3 + 2];
  const float* __restrict__ p = xyz + (size_t)b * NPTS * 3;
  int* __restrict__ out = ballidx + (size_t)gw * NSAMPLE;

  int cnt = 0, first = -1;
  for (int base = 0; base < NPTS; base += 64) {
    const int n = base + lane;
    const float dx = p[n * 3 + 0] - cx;
    const float dy = p[n * 3 + 1] - cy;
    const float dz = p[n * 3 + 2] - cz;
    const float d = __fadd_rn(__fadd_rn(__fmul_rn(dx, dx), __fmul_rn(dy, dy)),
                              __fmul_rn(dz, dz));
    const bool in = d < R2;
    const unsigned long long m = __ballot(in);
    if (first < 0 && m) first = base + __ffsll(m) - 1;
    const int pos = __popcll(m & ((1ull << lane) - 1ull));
    if (in && cnt + pos < NSAMPLE) out[cnt + pos] = n;
    cnt += __popcll(m);
    if (cnt >= NSAMPLE) break;
  }
  const int c = cnt < NSAMPLE ? cnt : NSAMPLE;
  for (int j = c + lane; j < NSAMPLE; j += 64) out[j] = first;
}

// ---------------------------------------------------------------------------
// Grouping + SharedMLP (131->64->64->128, ReLU) + max-pool over samples.
// One block (256 threads) per center. x staged in LDS [ch][64]; weights read
// from global transposed layout; bias folded into acc init; ReLU once after
// the max-pool (monotone => commutes).
// ---------------------------------------------------------------------------
__global__ __launch_bounds__(256) void mlp_kernel(
    const float* __restrict__ xyz, const float* __restrict__ feat,
    const float* __restrict__ newxyz, const int* __restrict__ ballidx,
    const float* __restrict__ w0t, const float* __restrict__ b0,
    const float* __restrict__ w1t, const float* __restrict__ b1,
    const float* __restrict__ w2t, const float* __restrict__ b2,
    float* __restrict__ out_feat)
{
  __shared__ float sA[CIN * 64];   // x (131x64); reused as h2 (64x64)
  __shared__ float sB[64 * 64];    // h1
  __shared__ int   s_idx[NSAMPLE];

  const int blk = blockIdx.x;
  const int b = blk >> 10, pc = blk & 1023;
  const int t = threadIdx.x;

  if (t < NSAMPLE) s_idx[t] = ballidx[(size_t)blk * NSAMPLE + t];
  __syncthreads();

  const int s = t & 63, cg = t >> 6;
  const int is = s_idx[s];
  const float* __restrict__ pb = xyz + (size_t)b * NPTS * 3;
  if (cg == 0) {
    const float cx = newxyz[blk * 3 + 0];
    const float cy = newxyz[blk * 3 + 1];
    const float cz = newxyz[blk * 3 + 2];
    sA[0 * 64 + s] = pb[is * 3 + 0] - cx;
    sA[1 * 64 + s] = pb[is * 3 + 1] - cy;
    sA[2 * 64 + s] = pb[is * 3 + 2] - cz;
  }
  const float* __restrict__ fb = feat + (size_t)b * NCH * NPTS;
  for (int c = cg; c < NCH; c += 4)
    sA[(3 + c) * 64 + s] = fb[(size_t)c * NPTS + is];
  __syncthreads();

  const int s0  = (t & 15) * 4;   // 4 samples
  const int oc0 = (t >> 4) * 4;   // 4 out-channels (layers 1,2)

  // ---- layer 1: CIN -> 64  (sA -> sB)
  {
    float acc[4][4];
#pragma unroll
    for (int j = 0; j < 4; ++j) {
      const float bj = b0[oc0 + j];
#pragma unroll
      for (int i = 0; i < 4; ++i) acc[i][j] = bj;
    }
    for (int ic = 0; ic < CIN; ++ic) {
      const float4 xv = *(const float4*)&sA[ic * 64 + s0];
      const float4 wv = *(const float4*)&w0t[ic * 64 + oc0];
      const float xr[4] = {xv.x, xv.y, xv.z, xv.w};
      const float wr[4] = {wv.x, wv.y, wv.z, wv.w};
#pragma unroll
      for (int i = 0; i < 4; ++i)
#pragma unroll
        for (int j = 0; j < 4; ++j) acc[i][j] += xr[i] * wr[j];
    }
#pragma unroll
    for (int j = 0; j < 4; ++j) {
      float4 r;
      r.x = fmaxf(acc[0][j], 0.f); r.y = fmaxf(acc[1][j], 0.f);
      r.z = fmaxf(acc[2][j], 0.f); r.w = fmaxf(acc[3][j], 0.f);
      *(float4*)&sB[(oc0 + j) * 64 + s0] = r;
    }
  }
  __syncthreads();

  // ---- layer 2: 64 -> 64  (sB -> sA, x is dead)
  {
    float acc[4][4];
#pragma unroll
    for (int j = 0; j < 4; ++j) {
      const float bj = b1[oc0 + j];
#pragma unroll
      for (int i = 0; i < 4; ++i) acc[i][j] = bj;
    }
    for (int ic = 0; ic < 64; ++ic) {
      const float4 xv = *(const float4*)&sB[ic * 64 + s0];
      const float4 wv = *(const float4*)&w1t[ic * 64 + oc0];
      const float xr[4] = {xv.x, xv.y, xv.z, xv.w};
      const float wr[4] = {wv.x, wv.y, wv.z, wv.w};
#pragma unroll
      for (int i = 0; i < 4; ++i)
#pragma unroll
        for (int j = 0; j < 4; ++j) acc[i][j] += xr[i] * wr[j];
    }
#pragma unroll
    for (int j = 0; j < 4; ++j) {
      float4 r;
      r.x = fmaxf(acc[0][j], 0.f); r.y = fmaxf(acc[1][j], 0.f);
      r.z = fmaxf(acc[2][j], 0.f); r.w = fmaxf(acc[3][j], 0.f);
      *(float4*)&sA[(oc0 + j) * 64 + s0] = r;
    }
  }
  __syncthreads();

  // ---- layer 3: 64 -> 128 + max-pool over 64 samples
  const int oc8 = (t >> 4) * 8;
  float acc[4][8];
#pragma unroll
  for (int j = 0; j < 8; ++j) {
    const float bj = b2[oc8 + j];
#pragma unroll
    for (int i = 0; i < 4; ++i) acc[i][j] = bj;
  }
  for (int ic = 0; ic < 64; ++ic) {
    const float4 xv  = *(const float4*)&sA[ic * 64 + s0];
    const float4 wlo = *(const float4*)&w2t[ic * 128 + oc8];
    const float4 whi = *(const float4*)&w2t[ic * 128 + oc8 + 4];
    const float xr[4] = {xv.x, xv.y, xv.z, xv.w};
    const float wr[8] = {wlo.x, wlo.y, wlo.z, wlo.w, whi.x, whi.y, whi.z, whi.w};
#pragma unroll
    for (int i = 0; i < 4; ++i)
#pragma unroll
      for (int j = 0; j < 8; ++j) acc[i][j] += xr[i] * wr[j];
  }
  float m[8];
#pragma unroll
  for (int j = 0; j < 8; ++j)
    m[j] = fmaxf(fmaxf(acc[0][j], acc[1][j]), fmaxf(acc[2][j], acc[3][j]));
#pragma unroll
  for (int off = 8; off >= 1; off >>= 1) {
#pragma unroll
    for (int j = 0; j < 8; ++j)
      m[j] = fmaxf(m[j], __shfl_xor(m[j], off, 64));
  }
  if ((t & 15) == 0) {
#pragma unroll
    for (int j = 0; j < 8; ++j)
      out_feat[((size_t)b * NCH + oc8 + j) * NPOINT + pc] = fmaxf(m[j], 0.f);
  }
}

// ---------------------------------------------------------------------------
extern "C" void kernel_launch(void* const* d_in, const int* in_sizes, int n_in,
                              void* d_out, int out_size, void* d_ws, size_t ws_size,
                              hipStream_t stream)
{
  const float* xyz  = (const float*)d_in[0];
  const float* feat = (const float*)d_in[1];
  const float* W0   = (const float*)d_in[2];
  const float* b0   = (const float*)d_in[3];
  const float* W1   = (const float*)d_in[4];
  const float* b1   = (const float*)d_in[5];
  const float* W2   = (const float*)d_in[6];
  const float* b2   = (const float*)d_in[7];

  float* out_newxyz = (float*)d_out;                               // 8*1024*3
  float* out_feat   = out_newxyz + (size_t)BATCH * NPOINT * 3;     // 8*128*1024
  float* out_inds_f = out_feat + (size_t)BATCH * NCH * NPOINT;     // 8*1024

  char* ws = (char*)d_ws;
  int*   ballidx = (int*)ws;                                       // 2 MB
  float* w0t = (float*)(ws + (size_t)BATCH * NPOINT * NSAMPLE * 4);
  float* w1t = w0t + 64 * CIN;
  float* w2t = w1t + 64 * 64;
  u64*   fsync = (u64*)(w2t + 64 * 128);   // 8 batches * 2 par * 4 subs * 8 words

  hipMemsetAsync(fsync, 0, (size_t)BATCH * 2 * FPS_SUBS * 8 * sizeof(u64), stream);
  fps_pipe_kernel<<<dim3(FPS_PAIRS * FPS_SUBS), dim3(FPS_THREADS), 0, stream>>>(
      xyz, out_newxyz, out_inds_f, fsync);
  wtrans_kernel<<<dim3((64 * CIN + 255) / 256), dim3(256), 0, stream>>>(
      W0, W1, W2, w0t, w1t, w2t);
  ballquery_kernel<<<dim3(BATCH * NPOINT / 4), dim3(256), 0, stream>>>(
      xyz, out_newxyz, ballidx);
  mlp_kernel<<<dim3(BATCH * NPOINT), dim3(256), 0, stream>>>(
      xyz, feat, out_newxyz, ballidx, w0t, b0, w1t, b1, w2t, b2, out_feat);
}

// Round 8
// 2723.536 us; speedup vs baseline: 1.2898x; 1.2898x over previous
//
#include <hip/hip_runtime.h>

#define BATCH   8
#define NPTS    16384
#define NCH     128
#define NPOINT  1024
#define NSAMPLE 64
#define CIN     131   // 3 + NCH

#define FPS_SUBS   4                          // blocks per batch (same XCD: bids == b mod 8)
#define THREADS    256
#define FPS_PPT    ((NPTS / FPS_SUBS) / THREADS)   // 16 points per thread
#define NWAVES     (THREADS / 64)                  // 4
#define CTAG       0x7C000000u

typedef unsigned long long u64;

__device__ __forceinline__ u64 u64max(u64 a, u64 b) { return a > b ? a : b; }

__device__ __forceinline__ u64 shfl_xor_u64(u64 v, int off) {
  const unsigned lo = __shfl_xor((unsigned)v, off, 64);
  const unsigned hi = __shfl_xor((unsigned)(v >> 32), off, 64);
  return ((u64)hi << 32) | lo;
}
__device__ __forceinline__ u64 shfl_u64(u64 v, int src) {
  const unsigned lo = __shfl((unsigned)v, src, 64);
  const unsigned hi = __shfl((unsigned)(v >> 32), src, 64);
  return ((u64)hi << 32) | lo;
}

// Poll 4 subs x 5 tagged words {val,idx,x,y,z}; winner = max val, tie -> lowest
// sub (subs own ascending index ranges => numpy first-occurrence preserved).
// Called by wave 0 only (20 active poll lanes).
__device__ __forceinline__ void poll_select(
    const u64* __restrict__ slots, int k, int lane,
    float& px, float& py, float& pz, int& widx)
{
  const int sub = lane >> 3, word = lane & 7;
  const bool active = (lane < 32) && (word < 5);
  u64 v = 0;
  if (active) {
    do {
      v = __hip_atomic_load(slots + sub * 8 + word, __ATOMIC_RELAXED,
                            __HIP_MEMORY_SCOPE_AGENT);
    } while ((int)(v >> 32) != k);
  }
  // butterfly max over lanes {0,8,16,24}; key = val<<2 | (3-sub)
  u64 key = ((u64)(unsigned)v << 2) | (u64)(3 - (sub & 3));
  key = u64max(key, shfl_xor_u64(key, 8));
  key = u64max(key, shfl_xor_u64(key, 16));
  const int wsub = 3 - (int)(shfl_u64(key, 0) & 3);
  widx = (int)(unsigned)shfl_u64(v, wsub * 8 + 1);
  px = __uint_as_float((unsigned)shfl_u64(v, wsub * 8 + 2));
  py = __uint_as_float((unsigned)shfl_u64(v, wsub * 8 + 3));
  pz = __uint_as_float((unsigned)shfl_u64(v, wsub * 8 + 4));
}

// Exact numpy order: d = ((dx*dx + dy*dy) + dz*dz), no fma; fminf; argmax
// first-occurrence. pk = valbits<<18 | (idx ^ 0x3FFFF): u64-max == (val max,
// idx min). Winning thread keeps its candidate's raw coords in registers.
#define FPS_STEP(xs, ys, zs, mind, px, py, pz, pkm, bx, by, bz)                \
  {                                                                            \
    float bestv = -1.0f; int besti = 0;                                        \
    _Pragma("unroll")                                                          \
    for (int i = 0; i < FPS_PPT; ++i) {                                        \
      const float dx = xs[i] - px, dy = ys[i] - py, dz = zs[i] - pz;           \
      const float d = __fadd_rn(__fadd_rn(__fmul_rn(dx, dx), __fmul_rn(dy, dy)),\
                                __fmul_rn(dz, dz));                            \
      const float m = fminf(mind[i], d);                                       \
      mind[i] = m;                                                             \
      if (m > bestv) { bestv = m; besti = base + t + i * THREADS;              \
                       bx = xs[i]; by = ys[i]; bz = zs[i]; }                   \
    }                                                                          \
    pkm = ((u64)__float_as_uint(bestv) << 18) | (u64)(besti ^ 0x3FFFF);        \
  }

#define FPS_PUBLISH(slots, k, bw, bx, by, bz)                                  \
  {                                                                            \
    const u64 tg = (u64)(k) << 32;                                             \
    u64* __restrict__ sl = (slots) + ((k) & 1) * (FPS_SUBS * 8) + s * 8;       \
    __hip_atomic_store(&sl[1], tg | (unsigned)(((bw) ^ 0x3FFFF) & 0x3FFFF),    \
                       __ATOMIC_RELAXED, __HIP_MEMORY_SCOPE_AGENT);            \
    __hip_atomic_store(&sl[2], tg | __float_as_uint(bx),                       \
                       __ATOMIC_RELAXED, __HIP_MEMORY_SCOPE_AGENT);            \
    __hip_atomic_store(&sl[3], tg | __float_as_uint(by),                       \
                       __ATOMIC_RELAXED, __HIP_MEMORY_SCOPE_AGENT);            \
    __hip_atomic_store(&sl[4], tg | __float_as_uint(bz),                       \
                       __ATOMIC_RELAXED, __HIP_MEMORY_SCOPE_AGENT);            \
    __hip_atomic_store(&sl[0], tg | (unsigned)((bw) >> 18),                    \
                       __ATOMIC_RELAXED, __HIP_MEMORY_SCOPE_AGENT);            \
    asm volatile("" ::: "memory");                                             \
  }

// ---------------------------------------------------------------------------
// Transpose weights into [ic][oc] layout (float4 loads in the MLP).
// ---------------------------------------------------------------------------
__global__ void wtrans_kernel(const float* __restrict__ W0,
                              const float* __restrict__ W1,
                              const float* __restrict__ W2,
                              float* __restrict__ w0t,
                              float* __restrict__ w1t,
                              float* __restrict__ w2t)
{
  const int t = blockIdx.x * blockDim.x + threadIdx.x;
  if (t < 64 * CIN) { const int oc = t / CIN, ic = t % CIN; w0t[ic * 64  + oc] = W0[t]; }
  if (t < 64 * 64)  { const int oc = t >> 6,  ic = t & 63;  w1t[ic * 64  + oc] = W1[t]; }
  if (t < 128 * 64) { const int oc = t / 64,  ic = t % 64;  w2t[ic * 128 + oc] = W2[t]; }
}

// ---------------------------------------------------------------------------
// Mega kernel: bids 0..31 = FPS (batch = bid&7 -> same XCD, sub = bid>>3);
// bids 32.. = one block per center (pc-major: readiness monotone in bid).
// Center blocks spin (s_sleep, 4 lanes) on tagged per-center slots written by
// the FPS leader, then do ball-query (4-wave scan + exact merge) + grouping +
// SharedMLP + max-pool (proven R3 code).
// ---------------------------------------------------------------------------
__global__ __launch_bounds__(THREADS) void mega_kernel(
    const float* __restrict__ xyz, const float* __restrict__ feat,
    const float* __restrict__ w0t, const float* __restrict__ b0,
    const float* __restrict__ w1t, const float* __restrict__ b1,
    const float* __restrict__ w2t, const float* __restrict__ b2,
    float* __restrict__ out_newxyz, float* __restrict__ out_feat,
    float* __restrict__ out_inds_f,
    u64* __restrict__ fsync, u64* __restrict__ cslot)
{
  __shared__ float sA[CIN * 64];     // grouped x (131x64); reused as h2
  __shared__ float sB[64 * 64];      // h1
  __shared__ int   s_idx[NSAMPLE];
  __shared__ int   bq[4][NSAMPLE];
  __shared__ int   bqcnt[4], bqfirst[4];
  __shared__ u64   s_w[NWAVES];
  __shared__ unsigned s_sel[4];

  const int t = threadIdx.x;

  if (blockIdx.x < BATCH * FPS_SUBS) {
    // ======================= FPS path =======================
    const int bid = blockIdx.x;
    const int b = bid & 7, s = bid >> 3;       // same-XCD subs
    const int lane = t & 63, wid = t >> 6;
    const int base = s * (NPTS / FPS_SUBS);
    const float* __restrict__ p = xyz + (size_t)b * NPTS * 3;

    float xs[FPS_PPT], ys[FPS_PPT], zs[FPS_PPT], mind[FPS_PPT];
#pragma unroll
    for (int i = 0; i < FPS_PPT; ++i) {
      const int n = base + t + i * THREADS;    // coalesced per wave
      xs[i] = p[n * 3 + 0];
      ys[i] = p[n * 3 + 1];
      zs[i] = p[n * 3 + 2];
      mind[i] = 1e10f;
    }

    u64* __restrict__ slots = fsync + (size_t)b * (2 * FPS_SUBS * 8);
    u64* __restrict__ cs    = cslot + (size_t)b * NPOINT * 4;

    float px = p[0], py = p[1], pz = p[2];
    if (s == 0 && t == 0) {
      out_inds_f[b * NPOINT] = 0.0f;
      const size_t o = (size_t)b * NPOINT * 3;
      out_newxyz[o + 0] = px; out_newxyz[o + 1] = py; out_newxyz[o + 2] = pz;
      const u64 tg = (u64)CTAG << 32;
      __hip_atomic_store(&cs[1], tg | __float_as_uint(px), __ATOMIC_RELAXED, __HIP_MEMORY_SCOPE_AGENT);
      __hip_atomic_store(&cs[2], tg | __float_as_uint(py), __ATOMIC_RELAXED, __HIP_MEMORY_SCOPE_AGENT);
      __hip_atomic_store(&cs[3], tg | __float_as_uint(pz), __ATOMIC_RELAXED, __HIP_MEMORY_SCOPE_AGENT);
      __hip_atomic_store(&cs[0], tg | 0u, __ATOMIC_RELAXED, __HIP_MEMORY_SCOPE_AGENT);
    }

    for (int k = 1; k < NPOINT; ++k) {
      u64 pk; float cx = 0.f, cy = 0.f, cz = 0.f;
      FPS_STEP(xs, ys, zs, mind, px, py, pz, pk, cx, cy, cz);
      {
        u64 r = pk;
#pragma unroll
        for (int off = 32; off >= 1; off >>= 1) r = u64max(r, shfl_xor_u64(r, off));
        if (lane == 0) s_w[wid] = r;
      }
      __syncthreads();
      {
        u64 bw = s_w[0];
#pragma unroll
        for (int i = 1; i < NWAVES; ++i) bw = u64max(bw, s_w[i]);
        if (pk == bw) FPS_PUBLISH(slots, k, bw, cx, cy, cz);   // exactly one thread
      }
      if (wid == 0) {
        int widx;
        float qx, qy, qz;
        poll_select(slots + (k & 1) * (FPS_SUBS * 8), k, lane, qx, qy, qz, widx);
        if (lane == 0) {
          s_sel[0] = (unsigned)widx;
          s_sel[1] = __float_as_uint(qx);
          s_sel[2] = __float_as_uint(qy);
          s_sel[3] = __float_as_uint(qz);
        }
      }
      __syncthreads();
      const int widx = (int)s_sel[0];
      px = __uint_as_float(s_sel[1]);
      py = __uint_as_float(s_sel[2]);
      pz = __uint_as_float(s_sel[3]);
      if (s == 0 && t == 0) {
        out_inds_f[b * NPOINT + k] = (float)widx;
        const size_t o = ((size_t)b * NPOINT + k) * 3;
        out_newxyz[o + 0] = px; out_newxyz[o + 1] = py; out_newxyz[o + 2] = pz;
        const u64 tg = (u64)(CTAG | (unsigned)k) << 32;
        u64* __restrict__ ck = cs + (size_t)k * 4;
        __hip_atomic_store(&ck[1], tg | s_sel[1], __ATOMIC_RELAXED, __HIP_MEMORY_SCOPE_AGENT);
        __hip_atomic_store(&ck[2], tg | s_sel[2], __ATOMIC_RELAXED, __HIP_MEMORY_SCOPE_AGENT);
        __hip_atomic_store(&ck[3], tg | s_sel[3], __ATOMIC_RELAXED, __HIP_MEMORY_SCOPE_AGENT);
        __hip_atomic_store(&ck[0], tg | (unsigned)widx, __ATOMIC_RELAXED, __HIP_MEMORY_SCOPE_AGENT);
      }
    }
    return;
  }

  // ======================= center path =======================
  const int c  = blockIdx.x - BATCH * FPS_SUBS;
  const int pc = c >> 3, b = c & 7;            // pc-major: readiness ~ bid order
  const u64* __restrict__ cs = cslot + ((size_t)b * NPOINT + pc) * 4;

  // spin until this center is published (all 4 words tagged)
  if (t < 4) {
    const unsigned tg = CTAG | (unsigned)pc;
    u64 v;
    for (;;) {
      v = __hip_atomic_load(cs + t, __ATOMIC_RELAXED, __HIP_MEMORY_SCOPE_AGENT);
      if ((unsigned)(v >> 32) == tg) break;
      __builtin_amdgcn_s_sleep(2);
    }
    s_sel[t] = (unsigned)v;
  }
  __syncthreads();
  const float cx = __uint_as_float(s_sel[1]);
  const float cy = __uint_as_float(s_sel[2]);
  const float cz = __uint_as_float(s_sel[3]);
  const float* __restrict__ pb = xyz + (size_t)b * NPTS * 3;

  // ---- ball query: 4 waves scan disjoint quarters; exact first-64 merge.
  {
    const int w = t >> 6, lane = t & 63;
    const float R2 = (float)(0.3 * 0.3);
    const int beg = w * (NPTS / 4);
    int cnt = 0, first = -1;
    for (int bs = beg; bs < beg + NPTS / 4; bs += 64) {
      const int n = bs + lane;
      const float dx = pb[n * 3 + 0] - cx;
      const float dy = pb[n * 3 + 1] - cy;
      const float dz = pb[n * 3 + 2] - cz;
      const float d = __fadd_rn(__fadd_rn(__fmul_rn(dx, dx), __fmul_rn(dy, dy)),
                                __fmul_rn(dz, dz));
      const bool in = d < R2;
      const u64 m = __ballot(in);
      if (first < 0 && m) first = bs + __ffsll(m) - 1;
      const int pos = __popcll(m & ((1ull << lane) - 1ull));
      if (in && cnt + pos < NSAMPLE) bq[w][cnt + pos] = n;
      cnt += __popcll(m);
      if (cnt >= NSAMPLE) break;
    }
    if (lane == 0) { bqcnt[w] = cnt < NSAMPLE ? cnt : NSAMPLE; bqfirst[w] = first; }
  }
  __syncthreads();
  if (t < NSAMPLE) {
    int firstAll = -1;
#pragma unroll
    for (int w = 0; w < 4; ++w)
      if (firstAll < 0 && bqfirst[w] >= 0) firstAll = bqfirst[w];
    int o = 0, val = -1;
#pragma unroll
    for (int w = 0; w < 4; ++w) {
      const int cw = bqcnt[w];
      if (val < 0 && t >= o && t < o + cw) val = bq[w][t - o];
      o += cw;
    }
    s_idx[t] = (val >= 0) ? val : firstAll;    // pad with first in-ball index
  }
  __syncthreads();

  // ---- grouping gather into LDS [ch][64]
  const int sm = t & 63, cg = t >> 6;
  const int is = s_idx[sm];
  if (cg == 0) {
    sA[0 * 64 + sm] = pb[is * 3 + 0] - cx;
    sA[1 * 64 + sm] = pb[is * 3 + 1] - cy;
    sA[2 * 64 + sm] = pb[is * 3 + 2] - cz;
  }
  const float* __restrict__ fb = feat + (size_t)b * NCH * NPTS;
  for (int ch = cg; ch < NCH; ch += 4)
    sA[(3 + ch) * 64 + sm] = fb[(size_t)ch * NPTS + is];
  __syncthreads();

  const int s0  = (t & 15) * 4;   // 4 samples
  const int oc0 = (t >> 4) * 4;   // 4 out-channels (layers 1,2)

  // ---- layer 1: CIN -> 64  (sA -> sB)
  {
    float acc[4][4];
#pragma unroll
    for (int j = 0; j < 4; ++j) {
      const float bj = b0[oc0 + j];
#pragma unroll
      for (int i = 0; i < 4; ++i) acc[i][j] = bj;
    }
    for (int ic = 0; ic < CIN; ++ic) {
      const float4 xv = *(const float4*)&sA[ic * 64 + s0];
      const float4 wv = *(const float4*)&w0t[ic * 64 + oc0];
      const float xr[4] = {xv.x, xv.y, xv.z, xv.w};
      const float wr[4] = {wv.x, wv.y, wv.z, wv.w};
#pragma unroll
      for (int i = 0; i < 4; ++i)
#pragma unroll
        for (int j = 0; j < 4; ++j) acc[i][j] += xr[i] * wr[j];
    }
#pragma unroll
    for (int j = 0; j < 4; ++j) {
      float4 r;
      r.x = fmaxf(acc[0][j], 0.f); r.y = fmaxf(acc[1][j], 0.f);
      r.z = fmaxf(acc[2][j], 0.f); r.w = fmaxf(acc[3][j], 0.f);
      *(float4*)&sB[(oc0 + j) * 64 + s0] = r;
    }
  }
  __syncthreads();

  // ---- layer 2: 64 -> 64  (sB -> sA)
  {
    float acc[4][4];
#pragma unroll
    for (int j = 0; j < 4; ++j) {
      const float bj = b1[oc0 + j];
#pragma unroll
      for (int i = 0; i < 4; ++i) acc[i][j] = bj;
    }
    for (int ic = 0; ic < 64; ++ic) {
      const float4 xv = *(const float4*)&sB[ic * 64 + s0];
      const float4 wv = *(const float4*)&w1t[ic * 64 + oc0];
      const float xr[4] = {xv.x, xv.y, xv.z, xv.w};
      const float wr[4] = {wv.x, wv.y, wv.z, wv.w};
#pragma unroll
      for (int i = 0; i < 4; ++i)
#pragma unroll
        for (int j = 0; j < 4; ++j) acc[i][j] += xr[i] * wr[j];
    }
#pragma unroll
    for (int j = 0; j < 4; ++j) {
      float4 r;
      r.x = fmaxf(acc[0][j], 0.f); r.y = fmaxf(acc[1][j], 0.f);
      r.z = fmaxf(acc[2][j], 0.f); r.w = fmaxf(acc[3][j], 0.f);
      *(float4*)&sA[(oc0 + j) * 64 + s0] = r;
    }
  }
  __syncthreads();

  // ---- layer 3: 64 -> 128 + max-pool over 64 samples
  const int oc8 = (t >> 4) * 8;
  float acc[4][8];
#pragma unroll
  for (int j = 0; j < 8; ++j) {
    const float bj = b2[oc8 + j];
#pragma unroll
    for (int i = 0; i < 4; ++i) acc[i][j] = bj;
  }
  for (int ic = 0; ic < 64; ++ic) {
    const float4 xv  = *(const float4*)&sA[ic * 64 + s0];
    const float4 wlo = *(const float4*)&w2t[ic * 128 + oc8];
    const float4 whi = *(const float4*)&w2t[ic * 128 + oc8 + 4];
    const float xr[4] = {xv.x, xv.y, xv.z, xv.w};
    const float wr[8] = {wlo.x, wlo.y, wlo.z, wlo.w, whi.x, whi.y, whi.z, whi.w};
#pragma unroll
    for (int i = 0; i < 4; ++i)
#pragma unroll
      for (int j = 0; j < 8; ++j) acc[i][j] += xr[i] * wr[j];
  }
  float m[8];
#pragma unroll
  for (int j = 0; j < 8; ++j)
    m[j] = fmaxf(fmaxf(acc[0][j], acc[1][j]), fmaxf(acc[2][j], acc[3][j]));
#pragma unroll
  for (int off = 8; off >= 1; off >>= 1) {
#pragma unroll
    for (int j = 0; j < 8; ++j)
      m[j] = fmaxf(m[j], __shfl_xor(m[j], off, 64));
  }
  if ((t & 15) == 0) {
#pragma unroll
    for (int j = 0; j < 8; ++j)
      out_feat[((size_t)b * NCH + oc8 + j) * NPOINT + pc] = fmaxf(m[j], 0.f);
  }
}

// ---------------------------------------------------------------------------
extern "C" void kernel_launch(void* const* d_in, const int* in_sizes, int n_in,
                              void* d_out, int out_size, void* d_ws, size_t ws_size,
                              hipStream_t stream)
{
  const float* xyz  = (const float*)d_in[0];
  const float* feat = (const float*)d_in[1];
  const float* W0   = (const float*)d_in[2];
  const float* b0   = (const float*)d_in[3];
  const float* W1   = (const float*)d_in[4];
  const float* b1   = (const float*)d_in[5];
  const float* W2   = (const float*)d_in[6];
  const float* b2   = (const float*)d_in[7];

  float* out_newxyz = (float*)d_out;                               // 8*1024*3
  float* out_feat   = out_newxyz + (size_t)BATCH * NPOINT * 3;     // 8*128*1024
  float* out_inds_f = out_feat + (size_t)BATCH * NCH * NPOINT;     // 8*1024

  char* ws = (char*)d_ws;
  u64* fsync = (u64*)ws;                                // 8*2*4*8 u64 = 4 KB
  u64* cslot = (u64*)(ws + 4096);                       // 8192*4 u64 = 256 KB
  float* w0t = (float*)(ws + 4096 + 262144);
  float* w1t = w0t + 64 * CIN;
  float* w2t = w1t + 64 * 64;

  hipMemsetAsync(ws, 0, 4096 + 262144, stream);         // fsync + cslot tags
  wtrans_kernel<<<dim3((64 * CIN + 255) / 256), dim3(256), 0, stream>>>(
      W0, W1, W2, w0t, w1t, w2t);
  mega_kernel<<<dim3(BATCH * FPS_SUBS + BATCH * NPOINT), dim3(THREADS), 0, stream>>>(
      xyz, feat, w0t, b0, w1t, b1, w2t, b2,
      out_newxyz, out_feat, out_inds_f, fsync, cslot);
}

// Round 9
// 2024.598 us; speedup vs baseline: 1.7351x; 1.3452x over previous
//
#include <hip/hip_runtime.h>

#define BATCH   8
#define NPTS    16384
#define NCH     128
#define NPOINT  1024
#define NSAMPLE 64
#define CIN     131   // 3 + NCH

#define THREADS  1024
#define FPS_PPT  (NPTS / THREADS)   // 16 points per thread
#define CTAG     0x7C000000u

typedef unsigned long long u64;

__device__ __forceinline__ u64 u64max(u64 a, u64 b) { return a > b ? a : b; }

__device__ __forceinline__ u64 shfl_xor_u64(u64 v, int off) {
  const unsigned lo = __shfl_xor((unsigned)v, off, 64);
  const unsigned hi = __shfl_xor((unsigned)(v >> 32), off, 64);
  return ((u64)hi << 32) | lo;
}

// ---------------------------------------------------------------------------
// Transpose weights into [ic][oc] layout (float4 loads in the MLP).
// ---------------------------------------------------------------------------
__global__ void wtrans_kernel(const float* __restrict__ W0,
                              const float* __restrict__ W1,
                              const float* __restrict__ W2,
                              float* __restrict__ w0t,
                              float* __restrict__ w1t,
                              float* __restrict__ w2t)
{
  const int t = blockIdx.x * blockDim.x + threadIdx.x;
  if (t < 64 * CIN) { const int oc = t / CIN, ic = t % CIN; w0t[ic * 64  + oc] = W0[t]; }
  if (t < 64 * 64)  { const int oc = t >> 6,  ic = t & 63;  w1t[ic * 64  + oc] = W1[t]; }
  if (t < 128 * 64) { const int oc = t / 64,  ic = t % 64;  w2t[ic * 128 + oc] = W2[t]; }
}

// ---------------------------------------------------------------------------
// Mega kernel, uniform 1024-thread blocks (16 waves @ VGPR>64 -> 1 block/CU,
// so the 8 FPS blocks own their CUs exclusively — no issue-slot theft).
// bids 0..7   : FPS, one block per batch, all 16384 points in-block.
//               Bit-exact numpy: d=((dx*dx+dy*dy)+dz*dz) no-fma, fminf,
//               argmax first-occurrence; ONE barrier/iter via parity s_w.
//               Leader publishes center {idx,x,y,z} to tagged cslot words.
// bids 8..8199: one block per center (pc-major => readiness ~ bid order).
//               Spin (4 lanes + s_sleep) -> ballquery (waves 0-3) ->
//               gather (16 waves) -> MLP (waves 0-3) -> maxpool -> store.
// ---------------------------------------------------------------------------
__global__ __launch_bounds__(THREADS) void mega_kernel(
    const float* __restrict__ xyz, const float* __restrict__ feat,
    const float* __restrict__ w0t, const float* __restrict__ b0,
    const float* __restrict__ w1t, const float* __restrict__ b1,
    const float* __restrict__ w2t, const float* __restrict__ b2,
    float* __restrict__ out_newxyz, float* __restrict__ out_feat,
    float* __restrict__ out_inds_f, u64* __restrict__ cslot)
{
  __shared__ float sA[CIN * 64];     // grouped x (131x64); reused as h2
  __shared__ float sB[64 * 64];      // h1
  __shared__ int   s_idx[NSAMPLE];
  __shared__ int   bq[4][NSAMPLE];
  __shared__ int   bqcnt[4], bqfirst[4];
  __shared__ u64   s_w[2][16];
  __shared__ unsigned s_sel[4];

  const int t = threadIdx.x;

  if (blockIdx.x < BATCH) {
    // ======================= FPS path (exclusive CU) =======================
    const int b = blockIdx.x;
    const int lane = t & 63, wid = t >> 6;
    const float* __restrict__ p = xyz + (size_t)b * NPTS * 3;

    float xs[FPS_PPT], ys[FPS_PPT], zs[FPS_PPT], mind[FPS_PPT];
#pragma unroll
    for (int i = 0; i < FPS_PPT; ++i) {
      const int n = t + i * THREADS;           // coalesced per wave
      xs[i] = p[n * 3 + 0];
      ys[i] = p[n * 3 + 1];
      zs[i] = p[n * 3 + 2];
      mind[i] = 1e10f;
    }

    u64* __restrict__ cs = cslot + (size_t)b * NPOINT * 4;

    float px = p[0], py = p[1], pz = p[2];
    if (t == 0) {
      out_inds_f[b * NPOINT] = 0.0f;
      const size_t o = (size_t)b * NPOINT * 3;
      out_newxyz[o + 0] = px; out_newxyz[o + 1] = py; out_newxyz[o + 2] = pz;
      const u64 tg = (u64)CTAG << 32;
      __hip_atomic_store(&cs[1], tg | __float_as_uint(px), __ATOMIC_RELAXED, __HIP_MEMORY_SCOPE_AGENT);
      __hip_atomic_store(&cs[2], tg | __float_as_uint(py), __ATOMIC_RELAXED, __HIP_MEMORY_SCOPE_AGENT);
      __hip_atomic_store(&cs[3], tg | __float_as_uint(pz), __ATOMIC_RELAXED, __HIP_MEMORY_SCOPE_AGENT);
      __hip_atomic_store(&cs[0], tg | 0u, __ATOMIC_RELAXED, __HIP_MEMORY_SCOPE_AGENT);
    }

    for (int k = 1; k < NPOINT; ++k) {
      const int par = k & 1;

      // local min-dist update + argmax (exact numpy order, no fma)
      float bestv = -1.0f;
      int   besti = 0;
#pragma unroll
      for (int i = 0; i < FPS_PPT; ++i) {
        const float dx = xs[i] - px;
        const float dy = ys[i] - py;
        const float dz = zs[i] - pz;
        const float d = __fadd_rn(__fadd_rn(__fmul_rn(dx, dx), __fmul_rn(dy, dy)),
                                  __fmul_rn(dz, dz));
        const float m = fminf(mind[i], d);
        mind[i] = m;
        if (m > bestv) { bestv = m; besti = t + i * THREADS; }
      }

      // pack: u64-max == (val max, idx min); idx<=16383 fits 18 bits
      u64 pk = ((u64)__float_as_uint(bestv) << 18) | (u64)(besti ^ 0x3FFFF);
#pragma unroll
      for (int off = 32; off >= 1; off >>= 1) pk = u64max(pk, shfl_xor_u64(pk, off));
      if (lane == 0) s_w[par][wid] = pk;
      __syncthreads();

      // all threads redundantly scan 16 slots (broadcast LDS reads)
      u64 bw = s_w[par][0];
#pragma unroll
      for (int i = 1; i < 16; ++i) bw = u64max(bw, s_w[par][i]);
      const int bi = (int)((~bw) & 0x3FFFF);

      // uniform-address coord load (L1-broadcast)
      px = p[bi * 3 + 0]; py = p[bi * 3 + 1]; pz = p[bi * 3 + 2];

      if (t == 0) {
        out_inds_f[b * NPOINT + k] = (float)bi;
        const size_t o = ((size_t)b * NPOINT + k) * 3;
        out_newxyz[o + 0] = px; out_newxyz[o + 1] = py; out_newxyz[o + 2] = pz;
        const u64 tg = (u64)(CTAG | (unsigned)k) << 32;
        u64* __restrict__ ck = cs + (size_t)k * 4;
        __hip_atomic_store(&ck[1], tg | __float_as_uint(px), __ATOMIC_RELAXED, __HIP_MEMORY_SCOPE_AGENT);
        __hip_atomic_store(&ck[2], tg | __float_as_uint(py), __ATOMIC_RELAXED, __HIP_MEMORY_SCOPE_AGENT);
        __hip_atomic_store(&ck[3], tg | __float_as_uint(pz), __ATOMIC_RELAXED, __HIP_MEMORY_SCOPE_AGENT);
        __hip_atomic_store(&ck[0], tg | (unsigned)bi, __ATOMIC_RELAXED, __HIP_MEMORY_SCOPE_AGENT);
      }
      // no 2nd barrier: next iter writes s_w[par^1]; wrap needs 2 barriers
    }
    return;
  }

  // ======================= center path =======================
  const int c  = blockIdx.x - BATCH;
  const int b = c & 7, pc = c >> 3;            // pc-major: readiness ~ bid order
  const u64* __restrict__ cs = cslot + ((size_t)b * NPOINT + pc) * 4;

  // spin until this center is published (all 4 words tagged)
  if (t < 4) {
    const unsigned tg = CTAG | (unsigned)pc;
    u64 v;
    for (;;) {
      v = __hip_atomic_load(cs + t, __ATOMIC_RELAXED, __HIP_MEMORY_SCOPE_AGENT);
      if ((unsigned)(v >> 32) == tg) break;
      __builtin_amdgcn_s_sleep(8);
    }
    s_sel[t] = (unsigned)v;
  }
  __syncthreads();
  const float cx = __uint_as_float(s_sel[1]);
  const float cy = __uint_as_float(s_sel[2]);
  const float cz = __uint_as_float(s_sel[3]);
  const float* __restrict__ pb = xyz + (size_t)b * NPTS * 3;

  // ---- ball query: waves 0-3 scan disjoint quarters; exact first-64 merge.
  if (t < 256) {
    const int w = t >> 6, lane = t & 63;
    const float R2 = (float)(0.3 * 0.3);
    const int beg = w * (NPTS / 4);
    int cnt = 0, first = -1;
    for (int bs = beg; bs < beg + NPTS / 4; bs += 64) {
      const int n = bs + lane;
      const float dx = pb[n * 3 + 0] - cx;
      const float dy = pb[n * 3 + 1] - cy;
      const float dz = pb[n * 3 + 2] - cz;
      const float d = __fadd_rn(__fadd_rn(__fmul_rn(dx, dx), __fmul_rn(dy, dy)),
                                __fmul_rn(dz, dz));
      const bool in = d < R2;
      const u64 m = __ballot(in);
      if (first < 0 && m) first = bs + __ffsll(m) - 1;
      const int pos = __popcll(m & ((1ull << lane) - 1ull));
      if (in && cnt + pos < NSAMPLE) bq[w][cnt + pos] = n;
      cnt += __popcll(m);
      if (cnt >= NSAMPLE) break;
    }
    if (lane == 0) { bqcnt[w] = cnt < NSAMPLE ? cnt : NSAMPLE; bqfirst[w] = first; }
  }
  __syncthreads();
  if (t < NSAMPLE) {
    int firstAll = -1;
#pragma unroll
    for (int w = 0; w < 4; ++w)
      if (firstAll < 0 && bqfirst[w] >= 0) firstAll = bqfirst[w];
    int o = 0, val = -1;
#pragma unroll
    for (int w = 0; w < 4; ++w) {
      const int cw = bqcnt[w];
      if (val < 0 && t >= o && t < o + cw) val = bq[w][t - o];
      o += cw;
    }
    s_idx[t] = (val >= 0) ? val : firstAll;    // pad with first in-ball index
  }
  __syncthreads();

  // ---- grouping gather into LDS [ch][64] using all 16 waves
  const int sm = t & 63, cg = t >> 6;          // cg = 0..15
  const int is = s_idx[sm];
  if (cg == 0) {
    sA[0 * 64 + sm] = pb[is * 3 + 0] - cx;
    sA[1 * 64 + sm] = pb[is * 3 + 1] - cy;
    sA[2 * 64 + sm] = pb[is * 3 + 2] - cz;
  }
  const float* __restrict__ fb = feat + (size_t)b * NCH * NPTS;
  for (int ch = cg; ch < NCH; ch += 16)
    sA[(3 + ch) * 64 + sm] = fb[(size_t)ch * NPTS + is];
  __syncthreads();

  const int s0  = (t & 15) * 4;   // 4 samples
  const int oc0 = ((t >> 4) & 15) * 4;

  // ---- layer 1: CIN -> 64  (sA -> sB), waves 0-3
  if (t < 256) {
    float acc[4][4];
#pragma unroll
    for (int j = 0; j < 4; ++j) {
      const float bj = b0[oc0 + j];
#pragma unroll
      for (int i = 0; i < 4; ++i) acc[i][j] = bj;
    }
    for (int ic = 0; ic < CIN; ++ic) {
      const float4 xv = *(const float4*)&sA[ic * 64 + s0];
      const float4 wv = *(const float4*)&w0t[ic * 64 + oc0];
      const float xr[4] = {xv.x, xv.y, xv.z, xv.w};
      const float wr[4] = {wv.x, wv.y, wv.z, wv.w};
#pragma unroll
      for (int i = 0; i < 4; ++i)
#pragma unroll
        for (int j = 0; j < 4; ++j) acc[i][j] += xr[i] * wr[j];
    }
#pragma unroll
    for (int j = 0; j < 4; ++j) {
      float4 r;
      r.x = fmaxf(acc[0][j], 0.f); r.y = fmaxf(acc[1][j], 0.f);
      r.z = fmaxf(acc[2][j], 0.f); r.w = fmaxf(acc[3][j], 0.f);
      *(float4*)&sB[(oc0 + j) * 64 + s0] = r;
    }
  }
  __syncthreads();

  // ---- layer 2: 64 -> 64  (sB -> sA), waves 0-3
  if (t < 256) {
    float acc[4][4];
#pragma unroll
    for (int j = 0; j < 4; ++j) {
      const float bj = b1[oc0 + j];
#pragma unroll
      for (int i = 0; i < 4; ++i) acc[i][j] = bj;
    }
    for (int ic = 0; ic < 64; ++ic) {
      const float4 xv = *(const float4*)&sB[ic * 64 + s0];
      const float4 wv = *(const float4*)&w1t[ic * 64 + oc0];
      const float xr[4] = {xv.x, xv.y, xv.z, xv.w};
      const float wr[4] = {wv.x, wv.y, wv.z, wv.w};
#pragma unroll
      for (int i = 0; i < 4; ++i)
#pragma unroll
        for (int j = 0; j < 4; ++j) acc[i][j] += xr[i] * wr[j];
    }
#pragma unroll
    for (int j = 0; j < 4; ++j) {
      float4 r;
      r.x = fmaxf(acc[0][j], 0.f); r.y = fmaxf(acc[1][j], 0.f);
      r.z = fmaxf(acc[2][j], 0.f); r.w = fmaxf(acc[3][j], 0.f);
      *(float4*)&sA[(oc0 + j) * 64 + s0] = r;
    }
  }
  __syncthreads();

  // ---- layer 3: 64 -> 128 + max-pool over 64 samples, waves 0-3
  if (t < 256) {
    const int oc8 = ((t >> 4) & 15) * 8;
    float acc[4][8];
#pragma unroll
    for (int j = 0; j < 8; ++j) {
      const float bj = b2[oc8 + j];
#pragma unroll
      for (int i = 0; i < 4; ++i) acc[i][j] = bj;
    }
    for (int ic = 0; ic < 64; ++ic) {
      const float4 xv  = *(const float4*)&sA[ic * 64 + s0];
      const float4 wlo = *(const float4*)&w2t[ic * 128 + oc8];
      const float4 whi = *(const float4*)&w2t[ic * 128 + oc8 + 4];
      const float xr[4] = {xv.x, xv.y, xv.z, xv.w};
      const float wr[8] = {wlo.x, wlo.y, wlo.z, wlo.w, whi.x, whi.y, whi.z, whi.w};
#pragma unroll
      for (int i = 0; i < 4; ++i)
#pragma unroll
        for (int j = 0; j < 8; ++j) acc[i][j] += xr[i] * wr[j];
    }
    float m[8];
#pragma unroll
    for (int j = 0; j < 8; ++j)
      m[j] = fmaxf(fmaxf(acc[0][j], acc[1][j]), fmaxf(acc[2][j], acc[3][j]));
#pragma unroll
    for (int off = 8; off >= 1; off >>= 1) {
#pragma unroll
      for (int j = 0; j < 8; ++j)
        m[j] = fmaxf(m[j], __shfl_xor(m[j], off, 64));
    }
    if ((t & 15) == 0) {
#pragma unroll
      for (int j = 0; j < 8; ++j)
        out_feat[((size_t)b * NCH + oc8 + j) * NPOINT + pc] = fmaxf(m[j], 0.f);
    }
  }
}

// ---------------------------------------------------------------------------
extern "C" void kernel_launch(void* const* d_in, const int* in_sizes, int n_in,
                              void* d_out, int out_size, void* d_ws, size_t ws_size,
                              hipStream_t stream)
{
  const float* xyz  = (const float*)d_in[0];
  const float* feat = (const float*)d_in[1];
  const float* W0   = (const float*)d_in[2];
  const float* b0   = (const float*)d_in[3];
  const float* W1   = (const float*)d_in[4];
  const float* b1   = (const float*)d_in[5];
  const float* W2   = (const float*)d_in[6];
  const float* b2   = (const float*)d_in[7];

  float* out_newxyz = (float*)d_out;                               // 8*1024*3
  float* out_feat   = out_newxyz + (size_t)BATCH * NPOINT * 3;     // 8*128*1024
  float* out_inds_f = out_feat + (size_t)BATCH * NCH * NPOINT;     // 8*1024

  char* ws = (char*)d_ws;
  u64* cslot = (u64*)ws;                                // 8192*4 u64 = 256 KB
  float* w0t = (float*)(ws + 262144);
  float* w1t = w0t + 64 * CIN;
  float* w2t = w1t + 64 * 64;

  hipMemsetAsync(cslot, 0, 262144, stream);             // clear center tags
  wtrans_kernel<<<dim3((64 * CIN + 255) / 256), dim3(256), 0, stream>>>(
      W0, W1, W2, w0t, w1t, w2t);
  mega_kernel<<<dim3(BATCH + BATCH * NPOINT), dim3(THREADS), 0, stream>>>(
      xyz, feat, w0t, b0, w1t, b1, w2t, b2,
      out_newxyz, out_feat, out_inds_f, cslot);
}